// Round 19
// baseline (184.021 us; speedup 1.0000x reference)
//
#include <hip/hip_runtime.h>

// Soft product quantizer — fused MFMA kernel, 1024 blocks (32 pairs each).
// z:(8,384,32,32) f32, C:(2048,384) f32. 4096 pairs (n,n+4096) x K=8, d=48, M=2048.
// s = 2<x,c> - |c|^2 (x^2 cancels; |s| small -> no max-subtract).
// prep: C -> bf16 tiles in ws (cs rows with -c2/2 at cols 48/49; ct transposed).
// 8 waves: rg=wv&1 (16-pair row group), ch2=wv>>1 (one 16-code quarter/tile).
// Pass1: S-MFMA + exp -> Z,T (LDS atomics). Pass2: S again -> P scatter into
// plds shared by mt-pair (dbuf, 1 barrier/tile) -> wave-role O-GEMM (role 0:
// Op, role 1: Oq; K=32) -> cross-JSD -> obuf combine -> store.
// Probe MFMAs label D-slots (mS=A-row, rS=B-col): correct under any bijective
// fragment layout.

typedef __attribute__((ext_vector_type(8))) short short8;
typedef __attribute__((ext_vector_type(4))) float f32x4;

#define Z_BCH   (384*1024)
#define JSD_IDX 3145728
#define CS_TILE 9216
#define CT_TILE 6912
#define CT_OFF  2359296

__device__ __forceinline__ f32x4 mfma32(short8 a, short8 b, f32x4 c) {
    return __builtin_amdgcn_mfma_f32_16x16x32_bf16(a, b, c, 0, 0, 0);
}
__device__ __forceinline__ unsigned short f2bf(float x) {
    unsigned u = __float_as_uint(x);
    u += 0x7FFF + ((u >> 16) & 1);
    return (unsigned short)(u >> 16);
}
__device__ __forceinline__ unsigned pk2bf(float a, float b) {
    return (unsigned)f2bf(a) | ((unsigned)f2bf(b) << 16);
}
__device__ __forceinline__ float bf2f(unsigned short h) {
    return __uint_as_float(((unsigned)h) << 16);
}

// ===================== prep: C -> bf16 tiles in ws =====================
__global__ __launch_bounds__(256)
void pq_prep(const float* __restrict__ Cb, unsigned char* __restrict__ ws)
{
    const int tid = threadIdx.x;
    const int k   = blockIdx.x >> 5;
    const int t   = blockIdx.x & 31;
    const int sm  = tid & 63, p8 = tid >> 6;
    const int m   = t*64 + sm;

    unsigned short* csT = (unsigned short*)(ws + (size_t)(k*32 + t)*CS_TILE);
    unsigned short* ctT = (unsigned short*)(ws + CT_OFF + (size_t)(k*32 + t)*CT_TILE);

    const float4* crow = (const float4*)(Cb + (size_t)m*384 + k*48);
    float4 va = crow[p8*3+0], vb = crow[p8*3+1], vc = crow[p8*3+2];
    const int d0 = p8*12;
    *(uint2*)(csT + sm*72 + d0 + 0) = make_uint2(pk2bf(va.x,va.y), pk2bf(va.z,va.w));
    *(uint2*)(csT + sm*72 + d0 + 4) = make_uint2(pk2bf(vb.x,vb.y), pk2bf(vb.z,vb.w));
    *(uint2*)(csT + sm*72 + d0 + 8) = make_uint2(pk2bf(vc.x,vc.y), pk2bf(vc.z,vc.w));
    ctT[(d0+ 0)*72+sm] = f2bf(va.x);  ctT[(d0+ 1)*72+sm] = f2bf(va.y);
    ctT[(d0+ 2)*72+sm] = f2bf(va.z);  ctT[(d0+ 3)*72+sm] = f2bf(va.w);
    ctT[(d0+ 4)*72+sm] = f2bf(vb.x);  ctT[(d0+ 5)*72+sm] = f2bf(vb.y);
    ctT[(d0+ 6)*72+sm] = f2bf(vb.z);  ctT[(d0+ 7)*72+sm] = f2bf(vb.w);
    ctT[(d0+ 8)*72+sm] = f2bf(vc.x);  ctT[(d0+ 9)*72+sm] = f2bf(vc.y);
    ctT[(d0+10)*72+sm] = f2bf(vc.z);  ctT[(d0+11)*72+sm] = f2bf(vc.w);
    if (tid < 64) {
        const float4* cr2 = (const float4*)(Cb + (size_t)(t*64 + tid)*384 + k*48);
        float c2 = 0.f;
#pragma unroll
        for (int i = 0; i < 12; ++i) {
            float4 v = cr2[i];
            c2 += v.x*v.x + v.y*v.y + v.z*v.z + v.w*v.w;
        }
        float mh = -0.5f*c2;
        unsigned short hi = f2bf(mh);
        unsigned short lo = f2bf(mh - bf2f(hi));
        *(uint2*)(csT + tid*72 + 48) = make_uint2((unsigned)hi | ((unsigned)lo << 16), 0u);
        *(uint2*)(csT + tid*72 + 52) = make_uint2(0u, 0u);
        *(uint2*)(csT + tid*72 + 56) = make_uint2(0u, 0u);
        *(uint2*)(csT + tid*72 + 60) = make_uint2(0u, 0u);
    }
}

// ===================== main fused kernel =====================
// LDS (53280 B): cs dbuf [2][9216] @0 | ct dbuf [2][6912] @18432 |
// plds dbuf [2][2rg x 2pgrp][32][40]u16 @32256 (20480) | ipz[64] @52736 |
// ent[64] @52992 | misc[8] @53248. Overlays: xs[64][72]u16 @0 (prologue);
// zt/tt 4x[32]f32 @32256 (pass1, dead before plds use); obuf @0 (epilogue).
__global__ __launch_bounds__(512, 4)
void pq_f(const float* __restrict__ Zin, const unsigned char* __restrict__ ws,
          float* __restrict__ Out)
{
    __shared__ __align__(16) unsigned char smem[53280];
    unsigned short* xs = (unsigned short*)smem;
    float* ztP  = (float*)(smem + 32256);
    float* ttP  = (float*)(smem + 32384);
    float* ztQ  = (float*)(smem + 32512);
    float* ttQ  = (float*)(smem + 32640);
    float* ipz  = (float*)(smem + 52736);   // [64]: 0-31 P, 32-63 Q
    float* ent  = (float*)(smem + 52992);
    float* misc = (float*)(smem + 53248);
    float* obuf = (float*)smem;

    const int tid  = threadIdx.x;
    const int lane = tid & 63;
    const int wv   = tid >> 6;          // 0..7
    const int rg   = wv & 1;            // 16-pair row group
    const int ch2  = wv >> 1;           // 0..3: mt = ch2
    const int lmt  = ch2 & 1;           // column block within shared plds
    const int pgrp = ch2 >> 1;          // plds group (mt pair)
    const int role = ch2 & 1;           // 0: Op, 1: Oq
    const int lr   = lane & 15;
    const int lg   = lane >> 4;
    const int pg   = blockIdx.x & 127;  // 128 pair-groups (32 pairs each)
    const int k    = blockIdx.x >> 7;

    // ---------- layout probes ----------
    short8 av, on;
#pragma unroll
    for (int i = 0; i < 8; ++i) { av[i] = (short)f2bf((float)lr); on[i] = (short)0x3F80; }
    f32x4 zf4 = {0.f,0.f,0.f,0.f};
    f32x4 dmv = mfma32(av, on, zf4);
    f32x4 drv = mfma32(on, av, zf4);
    int mS[4], rS[4];
#pragma unroll
    for (int j = 0; j < 4; ++j) {
        mS[j] = ((int)(dmv[j]*0.03125f + 0.5f)) & 15;
        rS[j] = ((int)(drv[j]*0.03125f + 0.5f)) & 15;
    }
    const bool packOK = __all(mS[1] == mS[0]+1 && mS[2] == mS[0]+2 && mS[3] == mS[0]+3
                              && rS[1] == rS[0] && rS[2] == rS[0] && rS[3] == rS[0]);

    const unsigned char* csg = ws + (size_t)(k*32)*CS_TILE;
    const unsigned char* ctg = ws + CT_OFF + (size_t)(k*32)*CT_TILE;

    // ---------- prologue: x -> xs -> register B-frags ----------
    for (int i = tid; i < 2304; i += 512) ((unsigned*)smem)[i] = 0u;   // zero xs
    if (tid < 128) ((float*)(smem + 32256))[tid] = 0.f;                // zt/tt
    __syncthreads();
    for (int i = tid; i < 3072; i += 512) {            // 64 rows x 48 dims
        int row = i & 63, d = i >> 6;
        int n = pg*32 + (row & 31) + ((row & 32) ? 4096 : 0);
        xs[row*72 + d] = f2bf(Zin[(size_t)(n >> 10)*Z_BCH + (k*48 + d)*1024 + (n & 1023)]);
    }
    if (tid < 64) { xs[tid*72 + 48] = 0x3F80; xs[tid*72 + 49] = 0x3F80; }
    __syncthreads();
    short8 xf[2][2];   // [p/q][k-half]; p row = rg*16+lr, q row = 32+rg*16+lr
#pragma unroll
    for (int kh = 0; kh < 2; ++kh) {
        xf[0][kh] = *(const short8*)(xs + (rg*16 + lr)*72 + kh*32 + lg*8);
        xf[1][kh] = *(const short8*)(xs + (32 + rg*16 + lr)*72 + kh*32 + lg*8);
    }
    __syncthreads();

    uint4 r0, r1, r2;
#define LOADREG(t) do {                                                       \
        const unsigned char* _c = csg + (size_t)(t)*CS_TILE;                  \
        r0 = *(const uint4*)(_c + tid*16);                                    \
        if (tid < 64) r1 = *(const uint4*)(_c + 8192 + tid*16);               \
    } while (0)
#define SWRITE(b) do {                                                        \
        *(uint4*)(smem + (b)*CS_TILE + tid*16) = r0;                          \
        if (tid < 64) *(uint4*)(smem + (b)*CS_TILE + 8192 + tid*16) = r1;     \
    } while (0)
#define LOADREG_CT(t) do {                                                    \
        LOADREG(t);                                                           \
        if (tid < 432) r2 = *(const uint4*)(ctg + (size_t)(t)*CT_TILE + tid*16); \
    } while (0)
#define SWRITE_CT(b) do {                                                     \
        SWRITE(b);                                                            \
        if (tid < 432) *(uint4*)(smem + 18432 + (b)*CT_TILE + tid*16) = r2;   \
    } while (0)

    // ================= pass 1: softmax stats =================
    float zp[4]={0,0,0,0}, tp[4]={0,0,0,0}, zq[4]={0,0,0,0}, tq[4]={0,0,0,0};

    LOADREG(0);
    SWRITE(0);
    LOADREG(1);
    __syncthreads();

#pragma unroll 1
    for (int t = 0; t < 32; ++t) {
        if (t < 31) SWRITE((t+1)&1);
        if (t < 30) LOADREG(t+2);
        const unsigned short* cst = (const unsigned short*)(smem + (t&1)*CS_TILE);
        short8 a0 = *(const short8*)(cst + (ch2*16 + lr)*72 + lg*8);
        short8 a1 = *(const short8*)(cst + (ch2*16 + lr)*72 + 32 + lg*8);
        f32x4 accP = {0.f,0.f,0.f,0.f}, accQ = {0.f,0.f,0.f,0.f};
        accP = mfma32(a0, xf[0][0], accP);
        accP = mfma32(a1, xf[0][1], accP);
        accQ = mfma32(a0, xf[1][0], accQ);
        accQ = mfma32(a1, xf[1][1], accQ);
#pragma unroll
        for (int j = 0; j < 4; ++j) {
            float sp = 2.f*accP[j], sq = 2.f*accQ[j];
            float e1 = __expf(sp), e2 = __expf(sq);
            zp[j] += e1; tp[j] = fmaf(e1, sp, tp[j]);
            zq[j] += e2; tq[j] = fmaf(e2, sq, tq[j]);
        }
        __syncthreads();
    }

#pragma unroll
    for (int j = 0; j < 4; ++j) {
        int r = rg*16 + rS[j];
        atomicAdd(ztP + r, zp[j]); atomicAdd(ttP + r, tp[j]);
        atomicAdd(ztQ + r, zq[j]); atomicAdd(ttQ + r, tq[j]);
    }
    __syncthreads();
    if (tid < 64) {   // row r = tid&31, isq = tid>>5
        int r = tid & 31;
        float z1 = (tid < 32) ? ztP[r] : ztQ[r];
        float t1 = (tid < 32) ? ttP[r] : ttQ[r];
        float i1 = 1.f/z1;
        ipz[tid] = i1;
        ent[tid] = t1*i1 - __logf(z1);
    }
    __syncthreads();
    float izp_s[4], izq_s[4];
#pragma unroll
    for (int j = 0; j < 4; ++j) {
        izp_s[j] = ipz[rg*16 + rS[j]];
        izq_s[j] = ipz[32 + rg*16 + rS[j]];
    }

    // ================= pass 2: P scatter (shared plds), role O-GEMM =================
    f32x4 Oa[3];
#pragma unroll
    for (int dt = 0; dt < 3; ++dt) Oa[dt] = (f32x4){0.f,0.f,0.f,0.f};
    float cross = 0.f;

    LOADREG_CT(0);
    SWRITE_CT(0);
    LOADREG_CT(1);
    __syncthreads();

#pragma unroll 1
    for (int t = 0; t < 32; ++t) {
        if (t < 31) SWRITE_CT((t+1)&1);
        if (t < 30) LOADREG_CT(t+2);
        const unsigned short* cst = (const unsigned short*)(smem + (t&1)*CS_TILE);
        const unsigned short* ctt = (const unsigned short*)(smem + 18432 + (t&1)*CT_TILE);
        unsigned short* pw = (unsigned short*)(smem + 32256 + ((t&1)*4 + rg*2 + pgrp)*2560);

        short8 a0 = *(const short8*)(cst + (ch2*16 + lr)*72 + lg*8);
        short8 a1 = *(const short8*)(cst + (ch2*16 + lr)*72 + 32 + lg*8);
        f32x4 accP = {0.f,0.f,0.f,0.f}, accQ = {0.f,0.f,0.f,0.f};
        accP = mfma32(a0, xf[0][0], accP);
        accP = mfma32(a1, xf[0][1], accP);
        accQ = mfma32(a0, xf[1][0], accQ);
        accQ = mfma32(a1, xf[1][1], accQ);
        float e1a[4], e2a[4];
#pragma unroll
        for (int j = 0; j < 4; ++j) {
            float e1 = __expf(2.f*accP[j]);
            float e2 = __expf(2.f*accQ[j]);
            e1a[j] = e1; e2a[j] = e2;
            float ss = fmaf(e1, izp_s[j], e2*izq_s[j]);
            cross = fmaf(ss, __logf(fmaf(0.5f, ss, 1e-12f)), cross);
        }
        if (packOK) {
            *(uint2*)(pw + rS[0]*40        + lmt*16 + mS[0]) =
                make_uint2(pk2bf(e1a[0], e1a[1]), pk2bf(e1a[2], e1a[3]));
            *(uint2*)(pw + (16 + rS[0])*40 + lmt*16 + mS[0]) =
                make_uint2(pk2bf(e2a[0], e2a[1]), pk2bf(e2a[2], e2a[3]));
        } else {
#pragma unroll
            for (int j = 0; j < 4; ++j) {
                pw[rS[j]*40        + lmt*16 + mS[j]] = f2bf(e1a[j]);
                pw[(16 + rS[j])*40 + lmt*16 + mS[j]] = f2bf(e2a[j]);
            }
        }
        // B-fragments (this wave's code pair-block) -> regs BEFORE the barrier
        short8 cB0 = *(const short8*)(ctt + (     lr)*72 + pgrp*32 + lg*8);
        short8 cB1 = *(const short8*)(ctt + (16 + lr)*72 + pgrp*32 + lg*8);
        short8 cB2 = *(const short8*)(ctt + (32 + lr)*72 + pgrp*32 + lg*8);
        __syncthreads();   // plds (both mt halves) ready
        {
            const unsigned short* pA = pw + (role ? 16 : 0)*40;
            short8 pAv = *(const short8*)(pA + lr*40 + lg*8);
            Oa[0] = mfma32(pAv, cB0, Oa[0]);
            Oa[1] = mfma32(pAv, cB1, Oa[1]);
            Oa[2] = mfma32(pAv, cB2, Oa[2]);
        }
    }

    // ---------------- epilogue ----------------
#pragma unroll
    for (int off = 1; off < 64; off <<= 1) cross += __shfl_xor(cross, off);
    if (lane == 0) misc[wv] = cross;
    __syncthreads();   // also: all O-MFMA done; cs/ct dead -> obuf safe

    if (pgrp == 1) {   // partial O (codes 32-63 of each tile) -> obuf
#pragma unroll
        for (int dt = 0; dt < 3; ++dt)
#pragma unroll
            for (int j = 0; j < 4; ++j)
                obuf[((rg*2 + role)*16 + mS[j])*48 + dt*16 + rS[j]] = Oa[dt][j];
    }
    __syncthreads();

    if (tid == 0) {
        float es = 0.f;
        for (int r = 0; r < 64; ++r) es += ent[r];
        float cr = 0.f;
        for (int w = 0; w < 8; ++w) cr += misc[w];
        atomicAdd(Out + JSD_IDX, (es - cr) * (0.5f/32768.f));
    }

    if (pgrp == 0) {   // combine, normalize, store (role 0: P rows, 1: Q rows)
#pragma unroll
        for (int dt = 0; dt < 3; ++dt)
#pragma unroll
            for (int j = 0; j < 4; ++j) {
                int xr = mS[j];
                int n = pg*32 + rg*16 + xr + (role ? 4096 : 0);
                int chc = k*48 + dt*16 + rS[j];
                float v = (Oa[dt][j] + obuf[((rg*2 + role)*16 + xr)*48 + dt*16 + rS[j]])
                          * ipz[role*32 + rg*16 + xr];
                Out[(size_t)(n >> 10)*Z_BCH + (size_t)chc*1024 + (n & 1023)] = v;
            }
    }
}

extern "C" void kernel_launch(void* const* d_in, const int* in_sizes, int n_in,
                              void* d_out, int out_size, void* d_ws, size_t ws_size,
                              hipStream_t stream)
{
    const float* z = (const float*)d_in[0];
    const float* C = (const float*)d_in[1];
    float* out = (float*)d_out;
    unsigned char* ws = (unsigned char*)d_ws;

    hipMemsetAsync(out + JSD_IDX, 0, sizeof(float), stream);

    pq_prep<<<dim3(256),  dim3(256), 0, stream>>>(C, ws);
    // 128 pair-groups (32 pairs each) x 8 subspaces = 1024 blocks
    pq_f   <<<dim3(1024), dim3(512), 0, stream>>>(z, ws, out);
}